// Round 1
// baseline (614.741 us; speedup 1.0000x reference)
//
#include <hip/hip_runtime.h>
#include <math.h>

#define N_NODES 10000
#define E_EDGES 320000
#define IN_DIM 128
#define EMB 128
#define HID 64
#define NEG_SLOPE 0.2f

typedef __attribute__((ext_vector_type(8))) short short8;     // 8 bf16 (4 VGPR)
typedef __attribute__((ext_vector_type(4))) short short4_t;   // 4 bf16
typedef __attribute__((ext_vector_type(4))) float floatx4;    // 4 fp32
typedef __attribute__((ext_vector_type(4))) int   intx4;
typedef __attribute__((ext_vector_type(2))) int   intx2;

// fp32 -> bf16 bits, round-to-nearest-even
__device__ __forceinline__ short f2bf(float f) {
    unsigned u = __float_as_uint(f);
    unsigned r = u + 0x7fffu + ((u >> 16) & 1u);
    return (short)(r >> 16);
}

__device__ __forceinline__ float sigmoidf_fast(float v) {
    return __builtin_amdgcn_rcpf(1.f + __expf(-v));
}

// ---------------------------------------------------------------------------
// Kernel A: h = relu(x @ dense_w + b); z = h @ gat_w; fused a_src/a_dst dots.
// 256 threads, 16 rows/block. Weights staged chunk-wise into LDS so global
// loads are batched+coalesced (no per-iteration dependent L2 load).
// GEMM2 wave layout: lanes = 64 cols of 4 rows -> shfl-reduce gives the
// attention dot products for free (removes att_kernel).
// ---------------------------------------------------------------------------
__global__ __launch_bounds__(256) void dense_gat_kernel(
    const float* __restrict__ x, const float* __restrict__ dw,
    const float* __restrict__ db, const float* __restrict__ gw,
    const float* __restrict__ asv, const float* __restrict__ adv,
    float* __restrict__ z, float* __restrict__ a_src, float* __restrict__ a_dst)
{
    __shared__ float xs[16][IN_DIM];     // 8 KB
    __shared__ float hs[16][EMB];        // 8 KB
    __shared__ float wsm[32 * 128];      // 16 KB: dw chunks [32][128] / gw [64][64]
    const int t = threadIdx.x;
    const int row0 = blockIdx.x * 16;    // 10000 % 16 == 0

    #pragma unroll
    for (int r = 0; r < 2; ++r) {
        const int idx = t + r * 256;           // 0..511 float4 slots
        const int row = idx >> 5, c4 = idx & 31;
        *(floatx4*)&xs[row][c4 * 4] =
            *(const floatx4*)&x[(row0 + row) * IN_DIM + c4 * 4];
    }

    // GEMM1: col = t&127, rows (t>>7)*8 .. +8
    const int col = t & 127, rb = (t >> 7) * 8;
    float acc[8];
    {
        const float bias = db[col];
        #pragma unroll
        for (int r = 0; r < 8; ++r) acc[r] = bias;
    }
    for (int ch = 0; ch < 4; ++ch) {
        __syncthreads();                       // xs ready (ch=0) / wsm reads done
        #pragma unroll
        for (int r = 0; r < 4; ++r) {          // stage dw[ch*32..+32][0..128]
            const int idx = t + r * 256;
            const int row = idx >> 5, c4 = idx & 31;
            *(floatx4*)&wsm[row * 128 + c4 * 4] =
                *(const floatx4*)&dw[(ch * 32 + row) * EMB + c4 * 4];
        }
        __syncthreads();
        #pragma unroll
        for (int jg = 0; jg < 8; ++jg) {
            const int jb = jg * 4;
            floatx4 xr[8];
            #pragma unroll
            for (int r = 0; r < 8; ++r)
                xr[r] = *(const floatx4*)&xs[rb + r][ch * 32 + jb];
            float wv[4];
            #pragma unroll
            for (int k = 0; k < 4; ++k) wv[k] = wsm[(jb + k) * 128 + col];
            #pragma unroll
            for (int k = 0; k < 4; ++k)
                #pragma unroll
                for (int r = 0; r < 8; ++r) acc[r] = fmaf(xr[r][k], wv[k], acc[r]);
        }
    }
    #pragma unroll
    for (int r = 0; r < 8; ++r) hs[rb + r][col] = fmaxf(acc[r], 0.f);

    // GEMM2: col2 = t&63, rows (t>>6)*4 .. +4
    const int col2 = t & 63, rb2 = (t >> 6) * 4;
    float acc2[4] = {0.f, 0.f, 0.f, 0.f};
    for (int ch = 0; ch < 2; ++ch) {
        __syncthreads();                       // hs ready / wsm reads done
        #pragma unroll
        for (int r = 0; r < 4; ++r) {          // stage gw[ch*64..+64][0..64]
            const int idx = t + r * 256;
            const int row = idx >> 4, c4 = idx & 15;
            *(floatx4*)&wsm[row * 64 + c4 * 4] =
                *(const floatx4*)&gw[(ch * 64 + row) * HID + c4 * 4];
        }
        __syncthreads();
        #pragma unroll
        for (int kg = 0; kg < 16; ++kg) {
            const int kb = kg * 4;
            floatx4 hr[4];
            #pragma unroll
            for (int r = 0; r < 4; ++r)
                hr[r] = *(const floatx4*)&hs[rb2 + r][ch * 64 + kb];
            float gv[4];
            #pragma unroll
            for (int k = 0; k < 4; ++k) gv[k] = wsm[(kb + k) * 64 + col2];
            #pragma unroll
            for (int k = 0; k < 4; ++k)
                #pragma unroll
                for (int r = 0; r < 4; ++r) acc2[r] = fmaf(hr[r][k], gv[k], acc2[r]);
        }
    }

    // store z + fused attention dot products (wave holds full row of 64 cols)
    const float as_c = asv[col2], ad_c = adv[col2];
    #pragma unroll
    for (int r = 0; r < 4; ++r) {
        z[(row0 + rb2 + r) * HID + col2] = acc2[r];
        float ps = acc2[r] * as_c;
        float pd = acc2[r] * ad_c;
        #pragma unroll
        for (int off = 32; off > 0; off >>= 1) {
            ps += __shfl_down(ps, off, 64);
            pd += __shfl_down(pd, off, 64);
        }
        if ((t & 63) == 0) {
            a_src[row0 + rb2 + r] = ps;
            a_dst[row0 + rb2 + r] = pd;
        }
    }
}

// ---------------------------------------------------------------------------
// Edge pipeline: counting sort by dst, then atomic-free aggregation.
// ---------------------------------------------------------------------------
__global__ __launch_bounds__(256) void count_kernel(
    const int* __restrict__ ei, int* __restrict__ cnt)
{
    const int e = blockIdx.x * blockDim.x + threadIdx.x;
    const int total = E_EDGES + N_NODES;
    if (e >= total) return;
    int s, d;
    if (e < E_EDGES) { s = ei[e]; d = ei[E_EDGES + e]; }
    else             { s = d = e - E_EDGES; }
    if ((unsigned)s >= N_NODES || (unsigned)d >= N_NODES) return;
    atomicAdd(&cnt[d], 1);
}

// single block, 256 threads, 40 items each. cnt staged into LDS coalesced.
__global__ __launch_bounds__(256) void scan_kernel(
    const int* __restrict__ cnt, int* __restrict__ offs, int* __restrict__ cursor)
{
    __shared__ int scnt[10240];
    __shared__ int part[256];
    const int t = threadIdx.x;
    #pragma unroll
    for (int r = 0; r < 10; ++r) {
        const int i4 = t + r * 256;            // 0..2559 int4 slots
        intx4 v = {0, 0, 0, 0};
        if (i4 < 2500) v = *(const intx4*)&cnt[i4 * 4];
        *(intx4*)&scnt[i4 * 4] = v;
    }
    __syncthreads();
    const int base = t * 40;
    int vals[40];
    int local = 0;
    #pragma unroll
    for (int i = 0; i < 40; ++i) { vals[i] = scnt[base + i]; local += vals[i]; }
    part[t] = local;
    __syncthreads();
    for (int off = 1; off < 256; off <<= 1) {   // Hillis-Steele inclusive
        const int v = (t >= off) ? part[t - off] : 0;
        __syncthreads();
        part[t] += v;
        __syncthreads();
    }
    int running = (t == 0) ? 0 : part[t - 1];   // exclusive base
    #pragma unroll
    for (int i = 0; i < 40; ++i) {
        const int idx = base + i;
        if (idx < N_NODES) { offs[idx] = running; cursor[idx] = running; }
        running += vals[i];
    }
    if (t == 255) offs[N_NODES] = running;
}

__global__ __launch_bounds__(256) void scatter_kernel(
    const int* __restrict__ ei, const float* __restrict__ a_src,
    const float* __restrict__ a_dst, int* __restrict__ cursor,
    intx2* __restrict__ se)
{
    const int e = blockIdx.x * blockDim.x + threadIdx.x;
    const int total = E_EDGES + N_NODES;
    if (e >= total) return;
    int s, d;
    if (e < E_EDGES) { s = ei[e]; d = ei[E_EDGES + e]; }
    else             { s = d = e - E_EDGES; }
    if ((unsigned)s >= N_NODES || (unsigned)d >= N_NODES) return;
    float v = a_src[s] + a_dst[d];
    v = (v > 0.f) ? v : NEG_SLOPE * v;
    const float w = __expf(v);          // max-shift skipped: |v| small, fp32 safe
    const int pos = atomicAdd(&cursor[d], 1);
    intx2 p;
    p[0] = s;
    p[1] = __float_as_int(w);
    se[pos] = p;                        // one 8B record instead of 2 arrays
}

// one wave per node; lane = feature dim. No atomics. Unrolled x2 so two
// dependent z-gathers are in flight per step.
__global__ __launch_bounds__(256) void aggregate_kernel(
    const int* __restrict__ offs, const intx2* __restrict__ se,
    const float* __restrict__ z, const float* __restrict__ gb,
    float* __restrict__ emb)
{
    const int wid  = (blockIdx.x * blockDim.x + threadIdx.x) >> 6;
    const int lane = threadIdx.x & 63;
    if (wid >= N_NODES) return;
    const int beg = offs[wid], end = offs[wid + 1];
    float acc = 0.f, sw = 0.f;
    int i = beg;
    for (; i + 2 <= end; i += 2) {
        const intx2 p0 = se[i];
        const intx2 p1 = se[i + 1];
        const float z0 = z[p0[0] * HID + lane];
        const float z1 = z[p1[0] * HID + lane];
        const float w0 = __int_as_float(p0[1]);
        const float w1 = __int_as_float(p1[1]);
        acc = fmaf(w0, z0, acc);
        acc = fmaf(w1, z1, acc);
        sw += w0 + w1;
    }
    if (i < end) {
        const intx2 p = se[i];
        const float w = __int_as_float(p[1]);
        acc = fmaf(w, z[p[0] * HID + lane], acc);
        sw += w;
    }
    emb[wid * HID + lane] = acc / sw + gb[lane];  // every node has a self loop
}

// ---------------------------------------------------------------------------
// Kernel D: sim = sigmoid(emb @ emb^T), SYMMETRIC. Upper-triangle tiles only
// (79*80/2 = 3160 blocks via folded 79x40 grid, bijective, no idle blocks).
// Each block computes one 128x128 tile with bf16 MFMA, sigmoids ONCE into a
// ping-pong f32 LDS scratch (stride 132 -> <=2-way banks = free), then writes
// BOTH orientations as float4 stores (>=64B row segments). The MFMA K-tree is
// order-identical for (i,j) and (j,i), so transposed values are bit-exact.
// ---------------------------------------------------------------------------
#define SROW 72
__global__ __launch_bounds__(256) void sim_kernel(
    const float* __restrict__ emb, float* __restrict__ sim)
{
    __shared__ short As[128 * SROW];   // 18432 B, reused as f32 scratch (ping)
    __shared__ short Bs[128 * SROW];   // 18432 B, reused as f32 scratch (pong)
    const int t    = threadIdx.x;
    const int lane = t & 63;
    const int wave = t >> 6;                 // 0..3
    const int wm   = (wave >> 1) * 64;
    const int wn   = (wave & 1) * 64;
    const int l15  = lane & 15;
    const int quad = lane >> 4;              // 0..3

    // upper-tri fold: grid (79, 40) -> (bi <= bj), 3160 blocks exactly
    int bi, bj;
    {
        const int gx = blockIdx.x, gy = blockIdx.y;
        if (gy <= gx) { bi = gy; bj = gx; }              // i in [0,40)
        else          { bi = 40 + gx; bj = 79 + gx - gy; } // i in [40,79)
    }

    // ---- stage both row-tiles as bf16 into LDS ----
    #pragma unroll
    for (int round = 0; round < 8; ++round) {
        const int idx = t + round * 256;     // 0..2047
        const int row = idx >> 4, c4 = idx & 15;
        int gr = bi * 128 + row; if (gr > N_NODES - 1) gr = N_NODES - 1;
        int gc = bj * 128 + row; if (gc > N_NODES - 1) gc = N_NODES - 1;
        const floatx4 a = *(const floatx4*)&emb[gr * HID + c4 * 4];
        const floatx4 b = *(const floatx4*)&emb[gc * HID + c4 * 4];
        short4_t sa, sb;
        #pragma unroll
        for (int j = 0; j < 4; ++j) { sa[j] = f2bf(a[j]); sb[j] = f2bf(b[j]); }
        *(short4_t*)&As[row * SROW + c4 * 4] = sa;
        *(short4_t*)&Bs[row * SROW + c4 * 4] = sb;
    }
    __syncthreads();

    // ---- fragments + MFMA (validated layout) ----
    short8 afrag[4][2];
    #pragma unroll
    for (int ti = 0; ti < 4; ++ti)
        #pragma unroll
        for (int ks = 0; ks < 2; ++ks)
            afrag[ti][ks] = *(const short8*)&As[(wm + ti * 16 + l15) * SROW +
                                                ks * 32 + quad * 8];

    floatx4 acc[4][4];
    const floatx4 zero = {0.f, 0.f, 0.f, 0.f};
    #pragma unroll
    for (int ti = 0; ti < 4; ++ti)
        #pragma unroll
        for (int tj = 0; tj < 4; ++tj) acc[ti][tj] = zero;

    #pragma unroll
    for (int tj = 0; tj < 4; ++tj) {
        const short8 bf0 = *(const short8*)&Bs[(wn + tj * 16 + l15) * SROW + quad * 8];
        const short8 bf1 = *(const short8*)&Bs[(wn + tj * 16 + l15) * SROW + 32 + quad * 8];
        #pragma unroll
        for (int ti = 0; ti < 4; ++ti) {
            acc[ti][tj] = __builtin_amdgcn_mfma_f32_16x16x32_bf16(
                afrag[ti][0], bf0, acc[ti][tj], 0, 0, 0);
            acc[ti][tj] = __builtin_amdgcn_mfma_f32_16x16x32_bf16(
                afrag[ti][1], bf1, acc[ti][tj], 0, 0, 0);
        }
    }
    __syncthreads();   // all LDS tile reads done before scratch reuse

    // ---- epilogue: sigmoid once into LDS, vectorized dual-orientation stores
    float* const scr0 = (float*)As;          // 32*132 floats = 16896 B used
    float* const scr1 = (float*)Bs;
    const int srow0 = (wave >> 1) * 16 + quad * 4;

    #pragma unroll
    for (int ti = 0; ti < 4; ++ti) {
        float* const scr = (ti & 1) ? scr1 : scr0;   // ping-pong: 1 sync/round
        #pragma unroll
        for (int reg = 0; reg < 4; ++reg)
            #pragma unroll
            for (int tj = 0; tj < 4; ++tj)
                scr[(srow0 + reg) * 132 + wn + tj * 16 + l15] =
                    sigmoidf_fast(acc[ti][tj][reg]);
        __syncthreads();

        // normal orientation: 32 rows x 128 cols, float4 stores (512B/row seg)
        #pragma unroll
        for (int round = 0; round < 4; ++round) {
            const int idx = t + round * 256;         // 0..1023
            const int rr = idx >> 5, c4 = idx & 31;
            const floatx4 v4 = *(const floatx4*)&scr[rr * 132 + c4 * 4];
            const int grow = bi * 128 +
                ((rr < 16) ? (ti * 16 + rr) : (64 + ti * 16 + rr - 16));
            const int gcol = bj * 128 + c4 * 4;
            if (grow < N_NODES && gcol < N_NODES)
                *(floatx4*)&sim[(unsigned)grow * N_NODES + gcol] = v4;
        }
        // transposed orientation: column-quads of scratch -> float4 along row
        if (bi != bj) {
            #pragma unroll
            for (int round = 0; round < 4; ++round) {
                const int idx = t + round * 256;     // 0..1023
                const int kq  = idx & 3;             // float4 slot within 16-block
                const int gcl = (idx >> 2) & 127;    // transposed row (col-local)
                const int blk = idx >> 9;            // 0/1: which 64-row half
                floatx4 v4;
                #pragma unroll
                for (int m = 0; m < 4; ++m)
                    v4[m] = scr[(blk * 16 + kq * 4 + m) * 132 + gcl];
                const int trow = bj * 128 + gcl;
                const int tcol = bi * 128 + blk * 64 + ti * 16 + kq * 4;
                if (trow < N_NODES && tcol < N_NODES)
                    *(floatx4*)&sim[(unsigned)trow * N_NODES + tcol] = v4;
            }
        }
        // no trailing sync needed: next ti writes the other buffer; the sync
        // inside ti+1 orders this buffer's reads vs ti+2's writes.
    }
}

// ---------------------------------------------------------------------------
extern "C" void kernel_launch(void* const* d_in, const int* in_sizes, int n_in,
                              void* d_out, int out_size, void* d_ws, size_t ws_size,
                              hipStream_t stream)
{
    const float* x   = (const float*)d_in[0];
    const int*   ei  = (const int*)d_in[1];   // edge_index int32 [2,E]
    const float* dw  = (const float*)d_in[2];
    const float* db  = (const float*)d_in[3];
    const float* gw  = (const float*)d_in[4];
    const float* asv = (const float*)d_in[5];
    const float* adv = (const float*)d_in[6];
    const float* gb  = (const float*)d_in[7];

    float* out = (float*)d_out;
    float* sim = out;                                   // [N*N]
    float* emb = out + (size_t)N_NODES * N_NODES;       // [N*HID]

    // Scratch (all dead before sim_kernel):
    // z 640000 | a_src 10000 | a_dst 10000 | cnt 10000 | offs 10001 |
    // cursor 10000 | pad 1 | se (int2) 330000*2  => 1,350,002 * 4B ~= 5.4 MB
    const size_t need = 1350002u * sizeof(float);
    float* ws = (ws_size >= need) ? (float*)d_ws : out;  // fallback: carve sim
    float* z      = ws;
    float* a_src  = ws + 640000;
    float* a_dst  = ws + 650000;
    int*   cnt    = (int*)(ws + 660000);
    int*   offs   = (int*)(ws + 670000);    // 10001
    int*   cursor = (int*)(ws + 680001);
    intx2* se     = (intx2*)(ws + 690002);  // +1 pad for 8B alignment

    hipMemsetAsync(cnt, 0, N_NODES * sizeof(int), stream);

    dense_gat_kernel<<<N_NODES / 16, 256, 0, stream>>>(x, dw, db, gw, asv, adv,
                                                       z, a_src, a_dst);

    const int total_edges = E_EDGES + N_NODES;
    const int eb = (total_edges + 255) / 256;
    count_kernel<<<eb, 256, 0, stream>>>(ei, cnt);
    scan_kernel<<<1, 256, 0, stream>>>(cnt, offs, cursor);
    scatter_kernel<<<eb, 256, 0, stream>>>(ei, a_src, a_dst, cursor, se);
    aggregate_kernel<<<(N_NODES * 64 + 255) / 256, 256, 0, stream>>>(
        offs, se, z, gb, emb);

    dim3 grid(79, 40);   // folded upper-triangle: 3160 blocks
    sim_kernel<<<grid, 256, 0, stream>>>(emb, sim);
}

// Round 2
// 563.881 us; speedup vs baseline: 1.0902x; 1.0902x over previous
//
#include <hip/hip_runtime.h>
#include <math.h>

#define N_NODES 10000
#define E_EDGES 320000
#define IN_DIM 128
#define EMB 128
#define HID 64
#define NEG_SLOPE 0.2f

typedef __attribute__((ext_vector_type(8))) short short8;     // 8 bf16 (4 VGPR)
typedef __attribute__((ext_vector_type(4))) short short4_t;   // 4 bf16
typedef __attribute__((ext_vector_type(4))) float floatx4;    // 4 fp32
typedef __attribute__((ext_vector_type(4))) int   intx4;
typedef __attribute__((ext_vector_type(2))) int   intx2;

// fp32 -> bf16 bits, round-to-nearest-even
__device__ __forceinline__ short f2bf(float f) {
    unsigned u = __float_as_uint(f);
    unsigned r = u + 0x7fffu + ((u >> 16) & 1u);
    return (short)(r >> 16);
}

__device__ __forceinline__ float sigmoidf_fast(float v) {
    return __builtin_amdgcn_rcpf(1.f + __expf(-v));
}

// ---------------------------------------------------------------------------
// Kernel A: h = relu(x @ dense_w + b); z = h @ gat_w; fused a_src/a_dst dots.
// 256 threads, 16 rows/block. Weights staged chunk-wise into LDS so global
// loads are batched+coalesced (no per-iteration dependent L2 load).
// ---------------------------------------------------------------------------
__global__ __launch_bounds__(256) void dense_gat_kernel(
    const float* __restrict__ x, const float* __restrict__ dw,
    const float* __restrict__ db, const float* __restrict__ gw,
    const float* __restrict__ asv, const float* __restrict__ adv,
    float* __restrict__ z, float* __restrict__ a_src, float* __restrict__ a_dst)
{
    __shared__ float xs[16][IN_DIM];     // 8 KB
    __shared__ float hs[16][EMB];        // 8 KB
    __shared__ float wsm[32 * 128];      // 16 KB: dw chunks [32][128] / gw [64][64]
    const int t = threadIdx.x;
    const int row0 = blockIdx.x * 16;    // 10000 % 16 == 0

    #pragma unroll
    for (int r = 0; r < 2; ++r) {
        const int idx = t + r * 256;           // 0..511 float4 slots
        const int row = idx >> 5, c4 = idx & 31;
        *(floatx4*)&xs[row][c4 * 4] =
            *(const floatx4*)&x[(row0 + row) * IN_DIM + c4 * 4];
    }

    // GEMM1: col = t&127, rows (t>>7)*8 .. +8
    const int col = t & 127, rb = (t >> 7) * 8;
    float acc[8];
    {
        const float bias = db[col];
        #pragma unroll
        for (int r = 0; r < 8; ++r) acc[r] = bias;
    }
    for (int ch = 0; ch < 4; ++ch) {
        __syncthreads();                       // xs ready (ch=0) / wsm reads done
        #pragma unroll
        for (int r = 0; r < 4; ++r) {          // stage dw[ch*32..+32][0..128]
            const int idx = t + r * 256;
            const int row = idx >> 5, c4 = idx & 31;
            *(floatx4*)&wsm[row * 128 + c4 * 4] =
                *(const floatx4*)&dw[(ch * 32 + row) * EMB + c4 * 4];
        }
        __syncthreads();
        #pragma unroll
        for (int jg = 0; jg < 8; ++jg) {
            const int jb = jg * 4;
            floatx4 xr[8];
            #pragma unroll
            for (int r = 0; r < 8; ++r)
                xr[r] = *(const floatx4*)&xs[rb + r][ch * 32 + jb];
            float wv[4];
            #pragma unroll
            for (int k = 0; k < 4; ++k) wv[k] = wsm[(jb + k) * 128 + col];
            #pragma unroll
            for (int k = 0; k < 4; ++k)
                #pragma unroll
                for (int r = 0; r < 8; ++r) acc[r] = fmaf(xr[r][k], wv[k], acc[r]);
        }
    }
    #pragma unroll
    for (int r = 0; r < 8; ++r) hs[rb + r][col] = fmaxf(acc[r], 0.f);

    // GEMM2: col2 = t&63, rows (t>>6)*4 .. +4
    const int col2 = t & 63, rb2 = (t >> 6) * 4;
    float acc2[4] = {0.f, 0.f, 0.f, 0.f};
    for (int ch = 0; ch < 2; ++ch) {
        __syncthreads();                       // hs ready / wsm reads done
        #pragma unroll
        for (int r = 0; r < 4; ++r) {          // stage gw[ch*64..+64][0..64]
            const int idx = t + r * 256;
            const int row = idx >> 4, c4 = idx & 15;
            *(floatx4*)&wsm[row * 64 + c4 * 4] =
                *(const floatx4*)&gw[(ch * 64 + row) * HID + c4 * 4];
        }
        __syncthreads();
        #pragma unroll
        for (int kg = 0; kg < 16; ++kg) {
            const int kb = kg * 4;
            floatx4 hr[4];
            #pragma unroll
            for (int r = 0; r < 4; ++r)
                hr[r] = *(const floatx4*)&hs[rb2 + r][ch * 64 + kb];
            float gv[4];
            #pragma unroll
            for (int k = 0; k < 4; ++k) gv[k] = wsm[(kb + k) * 64 + col2];
            #pragma unroll
            for (int k = 0; k < 4; ++k)
                #pragma unroll
                for (int r = 0; r < 4; ++r) acc2[r] = fmaf(hr[r][k], gv[k], acc2[r]);
        }
    }

    // store z + fused attention dot products (wave holds full row of 64 cols)
    const float as_c = asv[col2], ad_c = adv[col2];
    #pragma unroll
    for (int r = 0; r < 4; ++r) {
        z[(row0 + rb2 + r) * HID + col2] = acc2[r];
        float ps = acc2[r] * as_c;
        float pd = acc2[r] * ad_c;
        #pragma unroll
        for (int off = 32; off > 0; off >>= 1) {
            ps += __shfl_down(ps, off, 64);
            pd += __shfl_down(pd, off, 64);
        }
        if ((t & 63) == 0) {
            a_src[row0 + rb2 + r] = ps;
            a_dst[row0 + rb2 + r] = pd;
        }
    }
}

// ---------------------------------------------------------------------------
// Edge pipeline: counting sort by dst, then atomic-free aggregation.
// ---------------------------------------------------------------------------
__global__ __launch_bounds__(256) void count_kernel(
    const int* __restrict__ ei, int* __restrict__ cnt)
{
    const int e = blockIdx.x * blockDim.x + threadIdx.x;
    const int total = E_EDGES + N_NODES;
    if (e >= total) return;
    int s, d;
    if (e < E_EDGES) { s = ei[e]; d = ei[E_EDGES + e]; }
    else             { s = d = e - E_EDGES; }
    if ((unsigned)s >= N_NODES || (unsigned)d >= N_NODES) return;
    atomicAdd(&cnt[d], 1);
}

// single block, 256 threads, 40 items each. cnt staged into LDS coalesced.
__global__ __launch_bounds__(256) void scan_kernel(
    const int* __restrict__ cnt, int* __restrict__ offs, int* __restrict__ cursor)
{
    __shared__ int scnt[10240];
    __shared__ int part[256];
    const int t = threadIdx.x;
    #pragma unroll
    for (int r = 0; r < 10; ++r) {
        const int i4 = t + r * 256;            // 0..2559 int4 slots
        intx4 v = {0, 0, 0, 0};
        if (i4 < 2500) v = *(const intx4*)&cnt[i4 * 4];
        *(intx4*)&scnt[i4 * 4] = v;
    }
    __syncthreads();
    const int base = t * 40;
    int vals[40];
    int local = 0;
    #pragma unroll
    for (int i = 0; i < 40; ++i) { vals[i] = scnt[base + i]; local += vals[i]; }
    part[t] = local;
    __syncthreads();
    for (int off = 1; off < 256; off <<= 1) {   // Hillis-Steele inclusive
        const int v = (t >= off) ? part[t - off] : 0;
        __syncthreads();
        part[t] += v;
        __syncthreads();
    }
    int running = (t == 0) ? 0 : part[t - 1];   // exclusive base
    #pragma unroll
    for (int i = 0; i < 40; ++i) {
        const int idx = base + i;
        if (idx < N_NODES) { offs[idx] = running; cursor[idx] = running; }
        running += vals[i];
    }
    if (t == 255) offs[N_NODES] = running;
}

__global__ __launch_bounds__(256) void scatter_kernel(
    const int* __restrict__ ei, const float* __restrict__ a_src,
    const float* __restrict__ a_dst, int* __restrict__ cursor,
    intx2* __restrict__ se)
{
    const int e = blockIdx.x * blockDim.x + threadIdx.x;
    const int total = E_EDGES + N_NODES;
    if (e >= total) return;
    int s, d;
    if (e < E_EDGES) { s = ei[e]; d = ei[E_EDGES + e]; }
    else             { s = d = e - E_EDGES; }
    if ((unsigned)s >= N_NODES || (unsigned)d >= N_NODES) return;
    float v = a_src[s] + a_dst[d];
    v = (v > 0.f) ? v : NEG_SLOPE * v;
    const float w = __expf(v);          // max-shift skipped: |v| small, fp32 safe
    const int pos = atomicAdd(&cursor[d], 1);
    intx2 p;
    p[0] = s;
    p[1] = __float_as_int(w);
    se[pos] = p;                        // one 8B record instead of 2 arrays
}

// one wave per node; 4 edges in flight (16 lanes x float4 each) -> dependent
// load chain cut 4x. z row reads stay 256B coalesced. shfl_xor cross-group
// reduce, float4 emb store by group 0.
__global__ __launch_bounds__(256) void aggregate_kernel(
    const int* __restrict__ offs, const intx2* __restrict__ se,
    const float* __restrict__ z, const float* __restrict__ gb,
    float* __restrict__ emb)
{
    const int wid  = (blockIdx.x * blockDim.x + threadIdx.x) >> 6;
    const int lane = threadIdx.x & 63;
    if (wid >= N_NODES) return;
    const int g  = lane >> 4;            // edge subgroup 0..3
    const int c4 = (lane & 15) * 4;      // feature slot
    const int beg = offs[wid], end = offs[wid + 1];
    floatx4 acc = {0.f, 0.f, 0.f, 0.f};
    float sw = 0.f;
    for (int i = beg + g; i < end; i += 4) {
        const intx2 p = se[i];                                // broadcast in group
        const floatx4 zv = *(const floatx4*)&z[p[0] * HID + c4];
        const float w = __int_as_float(p[1]);
        acc += zv * w;
        sw  += w;
    }
    #pragma unroll
    for (int off = 16; off <= 32; off <<= 1) {
        #pragma unroll
        for (int k = 0; k < 4; ++k) acc[k] += __shfl_xor(acc[k], off, 64);
        sw += __shfl_xor(sw, off, 64);
    }
    if (g == 0) {
        const floatx4 gv = *(const floatx4*)&gb[c4];
        floatx4 r;
        #pragma unroll
        for (int k = 0; k < 4; ++k) r[k] = acc[k] / sw + gv[k];
        *(floatx4*)&emb[wid * HID + c4] = r;   // every node has a self loop
    }
}

// ---------------------------------------------------------------------------
// Kernel D: sim = sigmoid(emb @ emb^T), SYMMETRIC. Upper-triangle tiles only
// (79*80/2 = 3160 blocks via folded 79x40 grid, bijective). bf16 MFMA into
// 4x4 acc per wave, then sigmoid ONCE into a full-tile f32 LDS scratch
// [128][133] (68 KB, aliased over the bf16 staging buffers -> 2 blocks/CU),
// then BOTH orientations stored as 512B-contiguous float4 runs (32 lanes per
// row). Transposed LDS reads are 4-way bank conflicted (unavoidable for
// column gather at stride 4 rows) but LDS traffic is far off the store-BW
// critical path. MFMA K-tree order-identical for (i,j)/(j,i) -> transposed
// values bit-exact.
// ---------------------------------------------------------------------------
#define SROW 72
#define SCR_STRIDE 133
__global__ __launch_bounds__(256) void sim_kernel(
    const float* __restrict__ emb, float* __restrict__ sim)
{
    __shared__ float smem[128 * SCR_STRIDE];       // 68096 B
    short* const As = (short*)smem;                // [128*72] bf16, 18432 B
    short* const Bs = (short*)smem + 128 * SROW;   // next 18432 B
    const int t    = threadIdx.x;
    const int lane = t & 63;
    const int wave = t >> 6;                 // 0..3
    const int wm   = (wave >> 1) * 64;
    const int wn   = (wave & 1) * 64;
    const int l15  = lane & 15;
    const int quad = lane >> 4;              // 0..3

    // upper-tri fold: grid (79, 40) -> (bi <= bj), 3160 blocks exactly
    int bi, bj;
    {
        const int gx = blockIdx.x, gy = blockIdx.y;
        if (gy <= gx) { bi = gy; bj = gx; }                // bi in [0,40)
        else          { bi = 40 + gx; bj = 79 + gx - gy; } // bi in [40,79)
    }

    // ---- stage both row-tiles as bf16 into LDS ----
    #pragma unroll
    for (int round = 0; round < 8; ++round) {
        const int idx = t + round * 256;     // 0..2047
        const int row = idx >> 4, c4 = idx & 15;
        int gr = bi * 128 + row; if (gr > N_NODES - 1) gr = N_NODES - 1;
        int gc = bj * 128 + row; if (gc > N_NODES - 1) gc = N_NODES - 1;
        const floatx4 a = *(const floatx4*)&emb[gr * HID + c4 * 4];
        const floatx4 b = *(const floatx4*)&emb[gc * HID + c4 * 4];
        short4_t sa, sb;
        #pragma unroll
        for (int j = 0; j < 4; ++j) { sa[j] = f2bf(a[j]); sb[j] = f2bf(b[j]); }
        *(short4_t*)&As[row * SROW + c4 * 4] = sa;
        *(short4_t*)&Bs[row * SROW + c4 * 4] = sb;
    }
    __syncthreads();

    // ---- fragments + MFMA (validated layout) ----
    short8 afrag[4][2];
    #pragma unroll
    for (int ti = 0; ti < 4; ++ti)
        #pragma unroll
        for (int ks = 0; ks < 2; ++ks)
            afrag[ti][ks] = *(const short8*)&As[(wm + ti * 16 + l15) * SROW +
                                                ks * 32 + quad * 8];

    floatx4 acc[4][4];
    const floatx4 zero = {0.f, 0.f, 0.f, 0.f};
    #pragma unroll
    for (int ti = 0; ti < 4; ++ti)
        #pragma unroll
        for (int tj = 0; tj < 4; ++tj) acc[ti][tj] = zero;

    #pragma unroll
    for (int tj = 0; tj < 4; ++tj) {
        const short8 bf0 = *(const short8*)&Bs[(wn + tj * 16 + l15) * SROW + quad * 8];
        const short8 bf1 = *(const short8*)&Bs[(wn + tj * 16 + l15) * SROW + 32 + quad * 8];
        #pragma unroll
        for (int ti = 0; ti < 4; ++ti) {
            acc[ti][tj] = __builtin_amdgcn_mfma_f32_16x16x32_bf16(
                afrag[ti][0], bf0, acc[ti][tj], 0, 0, 0);
            acc[ti][tj] = __builtin_amdgcn_mfma_f32_16x16x32_bf16(
                afrag[ti][1], bf1, acc[ti][tj], 0, 0, 0);
        }
    }
    __syncthreads();   // all LDS tile reads done before scratch reuse

    // ---- sigmoid once into full-tile scratch ----
    // C/D layout: row = quad*4+reg (within 16), col = l15
    #pragma unroll
    for (int ti = 0; ti < 4; ++ti)
        #pragma unroll
        for (int reg = 0; reg < 4; ++reg)
            #pragma unroll
            for (int tj = 0; tj < 4; ++tj)
                smem[(wm + ti * 16 + quad * 4 + reg) * SCR_STRIDE +
                     wn + tj * 16 + l15] = sigmoidf_fast(acc[ti][tj][reg]);
    __syncthreads();

    // ---- normal orientation: 128 rows x 512B contiguous float4 runs ----
    #pragma unroll
    for (int round = 0; round < 16; ++round) {
        const int idx = t + round * 256;         // 0..4095
        const int rr = idx >> 5, cq = idx & 31;  // 32 lanes per row
        const int grow = bi * 128 + rr;
        const int gcol = bj * 128 + cq * 4;      // N%4==0 -> no partial vec
        if (grow < N_NODES && gcol < N_NODES) {
            const floatx4 v4 = *(const floatx4*)&smem[rr * SCR_STRIDE + cq * 4];
            *(floatx4*)&sim[(unsigned)grow * N_NODES + gcol] = v4;
        }
    }
    // ---- transposed orientation: column-gather from scratch, same stores ----
    if (bi != bj) {
        #pragma unroll
        for (int round = 0; round < 16; ++round) {
            const int idx = t + round * 256;
            const int rr = idx >> 5, cq = idx & 31;
            const int trow = bj * 128 + rr;
            const int tcol = bi * 128 + cq * 4;
            if (trow < N_NODES && tcol < N_NODES) {
                floatx4 v4;
                #pragma unroll
                for (int m = 0; m < 4; ++m)
                    v4[m] = smem[(cq * 4 + m) * SCR_STRIDE + rr];
                *(floatx4*)&sim[(unsigned)trow * N_NODES + tcol] = v4;
            }
        }
    }
}

// ---------------------------------------------------------------------------
extern "C" void kernel_launch(void* const* d_in, const int* in_sizes, int n_in,
                              void* d_out, int out_size, void* d_ws, size_t ws_size,
                              hipStream_t stream)
{
    const float* x   = (const float*)d_in[0];
    const int*   ei  = (const int*)d_in[1];   // edge_index int32 [2,E]
    const float* dw  = (const float*)d_in[2];
    const float* db  = (const float*)d_in[3];
    const float* gw  = (const float*)d_in[4];
    const float* asv = (const float*)d_in[5];
    const float* adv = (const float*)d_in[6];
    const float* gb  = (const float*)d_in[7];

    float* out = (float*)d_out;
    float* sim = out;                                   // [N*N]
    float* emb = out + (size_t)N_NODES * N_NODES;       // [N*HID]

    // Scratch (all dead before sim_kernel):
    // z 640000 | a_src 10000 | a_dst 10000 | cnt 10000 | offs 10001 |
    // cursor 10000 | pad 1 | se (int2) 330000*2  => 1,350,002 * 4B ~= 5.4 MB
    const size_t need = 1350002u * sizeof(float);
    float* ws = (ws_size >= need) ? (float*)d_ws : out;  // fallback: carve sim
    float* z      = ws;
    float* a_src  = ws + 640000;
    float* a_dst  = ws + 650000;
    int*   cnt    = (int*)(ws + 660000);
    int*   offs   = (int*)(ws + 670000);    // 10001
    int*   cursor = (int*)(ws + 680001);
    intx2* se     = (intx2*)(ws + 690002);  // +1 pad for 8B alignment

    hipMemsetAsync(cnt, 0, N_NODES * sizeof(int), stream);

    dense_gat_kernel<<<N_NODES / 16, 256, 0, stream>>>(x, dw, db, gw, asv, adv,
                                                       z, a_src, a_dst);

    const int total_edges = E_EDGES + N_NODES;
    const int eb = (total_edges + 255) / 256;
    count_kernel<<<eb, 256, 0, stream>>>(ei, cnt);
    scan_kernel<<<1, 256, 0, stream>>>(cnt, offs, cursor);
    scatter_kernel<<<eb, 256, 0, stream>>>(ei, a_src, a_dst, cursor, se);
    aggregate_kernel<<<(N_NODES * 64 + 255) / 256, 256, 0, stream>>>(
        offs, se, z, gb, emb);

    dim3 grid(79, 40);   // folded upper-triangle: 3160 blocks
    sim_kernel<<<grid, 256, 0, stream>>>(emb, sim);
}